// Round 7
// baseline (102.328 us; speedup 1.0000x reference)
//
#include <hip/hip_runtime.h>
#include <hip/hip_fp16.h>
#include <stdint.h>

// ALCOVE RBF: out[b,e] = exp(-C * sum_d attn[d] * |E[e,d] - X[b,d]|)
// BATCH=2048, NE=2048, ND=128, f32 in/out.
//
// R7: fp16-packed LDS operands, fp32 compute, 4 waves/SIMD, one barrier.
// Evidence: R2 vs R6 shows the mn=16 fp32-LDS pattern is LDS-pipe-bound
// (2 b128 reads per 16 terms ~ 24.5us/CU); VALU-bound configs realize
// ~1.1x of floor, LDS-bound ones ~1.3x+. Packing dim-PAIRS as half2 makes
// 2 b128 reads serve 32 terms (LDS ~12us), with fp32 sub + v_add(|a|,|b|)
// (full-rate, m07) at 2 inst/term + 0.5 cvt/term -> ~17us VALU floor.
// Precision: fp16 quantization of attn-scaled operands (<=0.08) was proven
// in R5 (absmax 4.9e-4); fp32 accumulation here is strictly better.
//
// Layout: block 256 thr = 4 waves; tile 64(b) x 64(e); whole K staged once:
// Eh/Xh[dd][row] half2 (dims 2dd,2dd+1), 16 KB each -> 32 KB, 4 blocks/CU.
// Compute: tx=tid&15 -> e=4tx..+3 (b128, 16 addrs, 4-lane-shared: free);
// ty=tid>>4 -> b=4ty..+3 (b128, 4 addrs/wave, 16-lane broadcast: free).
// No inline asm: LLVM folds fabsf(u)+fabsf(v) into v_add_f32 |u|,|v|.

#define ND 128
#define NEC 2048
#define CCONST 6.5f

static __device__ __forceinline__ uint32_t pack2(float lo, float hi) {
  union { __half2 h; uint32_t u; } cv;
  cv.h = __floats2half2_rn(lo, hi);   // v_cvt_pkrtz_f16_f32 (1 inst)
  return cv.u;
}

static __device__ __forceinline__ float2 unp2(uint32_t u) {
  union { uint32_t u; __half2 h; } cv;
  cv.u = u;
  return __half22float2(cv.h);        // 2x v_cvt_f32_f16
}

__global__ __launch_bounds__(256, 4)
void alcove_rbf_kernel(const float* __restrict__ X,
                       const float* __restrict__ E,
                       const float* __restrict__ A,
                       float* __restrict__ out) {
  __shared__ __align__(16) uint32_t Eh[64 * 64];  // [dd][e] half2 pairs, 16 KB
  __shared__ __align__(16) uint32_t Xh[64 * 64];  // [dd][b]              16 KB

  const int tid = threadIdx.x;
  const int e0 = blockIdx.x * 64;
  const int b0 = blockIdx.y * 64;

  // ---- stage whole K once: scale by attn (f32), pack half2 dim-pairs ----
  // 4 consecutive lanes take 4 consecutive float4s of one row (64B chunks).
  // LDS writes: 4-way bank conflict, ~600 cyc/wave total (negligible).
  {
    const int lane_in = tid & 3;
    const int r = tid >> 2;                       // row 0..63
    const float4* Ap = reinterpret_cast<const float4*>(A);
    const float4* Xp = reinterpret_cast<const float4*>(X + (size_t)(b0 + r) * ND);
    const float4* Ep = reinterpret_cast<const float4*>(E + (size_t)(e0 + r) * ND);
#pragma unroll
    for (int k = 0; k < 8; ++k) {
      int c4 = 4 * k + lane_in;                   // float4 col 0..31
      float4 a = Ap[c4];
      float4 xv = Xp[c4];
      float4 ev = Ep[c4];
      int dd = 2 * c4;                            // dim-pair index
      Xh[(dd + 0) * 64 + r] = pack2(xv.x * a.x, xv.y * a.y);
      Xh[(dd + 1) * 64 + r] = pack2(xv.z * a.z, xv.w * a.w);
      Eh[(dd + 0) * 64 + r] = pack2(ev.x * a.x, ev.y * a.y);
      Eh[(dd + 1) * 64 + r] = pack2(ev.z * a.z, ev.w * a.w);
    }
  }
  __syncthreads();  // the ONLY barrier

  const int tx = tid & 15;            // e = e0 + 4*tx + i
  const int ty = tid >> 4;            // b = b0 + 4*ty + j (wave w: ty=4w..4w+3)

  float acc[4][4];
#pragma unroll
  for (int j = 0; j < 4; ++j)
#pragma unroll
    for (int i = 0; i < 4; ++i) acc[j][i] = 0.f;

  const uint4* Ev = reinterpret_cast<const uint4*>(Eh);
  const uint4* Xv = reinterpret_cast<const uint4*>(Xh);

#pragma unroll 4
  for (int dd = 0; dd < 64; ++dd) {
    uint4 eu = Ev[dd * 16 + tx];      // e=4tx..+3, dims (2dd,2dd+1)
    uint4 xu = Xv[dd * 16 + ty];      // b=4ty..+3 (16-lane broadcast)
    float2 fe[4], fb[4];
    fe[0] = unp2(eu.x); fe[1] = unp2(eu.y); fe[2] = unp2(eu.z); fe[3] = unp2(eu.w);
    fb[0] = unp2(xu.x); fb[1] = unp2(xu.y); fb[2] = unp2(xu.z); fb[3] = unp2(xu.w);
#pragma unroll
    for (int j = 0; j < 4; ++j)
#pragma unroll
      for (int i = 0; i < 4; ++i) {
        // sub, sub, v_add_f32 |.|,|.| , add-to-acc = 4 inst / 2 terms
        acc[j][i] += fabsf(fb[j].x - fe[i].x) + fabsf(fb[j].y - fe[i].y);
      }
  }

  // ---- epilogue: exp + coalesced float4 stores ----
#pragma unroll
  for (int j = 0; j < 4; ++j) {
    int b = b0 + 4 * ty + j;
    float4 o;
    o.x = __expf(-CCONST * acc[j][0]);
    o.y = __expf(-CCONST * acc[j][1]);
    o.z = __expf(-CCONST * acc[j][2]);
    o.w = __expf(-CCONST * acc[j][3]);
    reinterpret_cast<float4*>(out + (size_t)b * NEC + e0)[tx] = o;
  }
}

extern "C" void kernel_launch(void* const* d_in, const int* in_sizes, int n_in,
                              void* d_out, int out_size, void* d_ws, size_t ws_size,
                              hipStream_t stream) {
  const float* X = (const float*)d_in[0];   // inputs    (2048,128)
  const float* E = (const float*)d_in[1];   // exemplars (2048,128)
  const float* A = (const float*)d_in[2];   // attn      (128,)
  float* out = (float*)d_out;               // (2048,2048)

  dim3 grid(NEC / 64, 2048 / 64);           // (32,32) = 1024 blocks = 4/CU
  dim3 block(256);
  alcove_rbf_kernel<<<grid, block, 0, stream>>>(X, E, A, out);
}